// Round 6
// baseline (37.104 us; speedup 1.0000x reference)
//
#include <hip/hip_runtime.h>

constexpr int N = 8192;
// MIN_DIST = RADIUS*2*scale = 1.0f;  TRI = N(N+1)/2, exact in f32
constexpr float TRI = 33558528.0f;

__device__ __forceinline__ float fsqrt(float v) { return __builtin_amdgcn_sqrtf(v); }

// Fused kernel, 1536 blocks:
//  blocks [0,1024):    pair tiles — 8 rows: {4b..4b+3} (top) + {N-4b-4..N-4b-1} (bot),
//                      upper-triangle scan j >= i, 4 j's per lane via float4.
//                        row_sd[i] = sum_{j>=i} d(i,j)
//                        row_sm[i] = sum_{j>=i} min(d,1)
//  blocks [1024,1536): masked-prefix-run correction, 16 rows/block, 4 rows/wave,
//                      256 j's per ballot step (4/lane via float4):
//                        row_corr[i] = sum over run [i,k) of (1-d), k = first d>1.
__global__ __launch_bounds__(256, 4)
void main_kernel(const float* __restrict__ x, const float* __restrict__ y,
                 const float* __restrict__ z,
                 float* __restrict__ row_sd, float* __restrict__ row_sm,
                 float* __restrict__ row_corr) {
    const int tid  = threadIdx.x;
    const int lane = tid & 63;
    const int wave = tid >> 6;

    if (blockIdx.x < 1024) {
        const int b       = blockIdx.x;
        const int topBase = 4 * b;            // 0..4092
        const int botBase = N - 4 * (b + 1);  // 8188..4096

        // Row coordinates: block-uniform -> SGPRs.
        float xr[8], yr[8], zr[8];
#pragma unroll
        for (int r = 0; r < 4; ++r) {
            xr[r]     = x[topBase + r]; yr[r]     = y[topBase + r]; zr[r]     = z[topBase + r];
            xr[4 + r] = x[botBase + r]; yr[4 + r] = y[botBase + r]; zr[4 + r] = z[botBase + r];
        }
        float sd[8], sm[8];
#pragma unroll
        for (int r = 0; r < 8; ++r) { sd[r] = 0.f; sm[r] = 0.f; }

#pragma unroll
        for (int g = 0; g < 2; ++g) {
            const int base = g ? botBase : topBase;  // multiple of 4
            const int ro   = g * 4;

            // head chunk [base, base+1024): predicated vs diagonal and N.
            // jj is a multiple of 4, so lane participation is all-or-nothing
            // and the clamped load never mixes valid/invalid elements.
            {
                const int   jj = base + 4 * tid;
                const int   cj = (jj <= N - 4) ? jj : (N - 4);
                const float4 vx = *(const float4*)(x + cj);
                const float4 vy = *(const float4*)(y + cj);
                const float4 vz = *(const float4*)(z + cj);
                const float ax[4] = {vx.x, vx.y, vx.z, vx.w};
                const float ay[4] = {vy.x, vy.y, vy.z, vy.w};
                const float az[4] = {vz.x, vz.y, vz.z, vz.w};
                const bool  valid = jj < N;
#pragma unroll
                for (int r = 0; r < 4; ++r) {
#pragma unroll
                    for (int q = 0; q < 4; ++q) {
                        const float dx = ax[q] - xr[ro + r];
                        const float dy = ay[q] - yr[ro + r];
                        const float dz = az[q] - zr[ro + r];
                        const float d  = fsqrt(dx * dx + dy * dy + dz * dz);
                        if (valid && (4 * tid + q) >= r) {
                            sd[ro + r] += d; sm[ro + r] += fminf(d, 1.f);
                        }
                    }
                }
            }
            // full middle 1024-chunks: predicate-free, software-pipelined float4 loads
            int j0 = base + 1024;
            if (j0 + 1024 <= N) {
                int idx = j0 + 4 * tid;
                float4 vx = *(const float4*)(x + idx);
                float4 vy = *(const float4*)(y + idx);
                float4 vz = *(const float4*)(z + idx);
                while (true) {
                    const float ax[4] = {vx.x, vx.y, vx.z, vx.w};
                    const float ay[4] = {vy.x, vy.y, vy.z, vy.w};
                    const float az[4] = {vz.x, vz.y, vz.z, vz.w};
                    const bool  more = (j0 + 2048 <= N);
                    if (more) {
                        idx += 1024;
                        vx = *(const float4*)(x + idx);
                        vy = *(const float4*)(y + idx);
                        vz = *(const float4*)(z + idx);
                    }
#pragma unroll
                    for (int r = 0; r < 4; ++r) {
                        float dsum = 0.f, msum = 0.f;
#pragma unroll
                        for (int q = 0; q < 4; ++q) {
                            const float dx = ax[q] - xr[ro + r];
                            const float dy = ay[q] - yr[ro + r];
                            const float dz = az[q] - zr[ro + r];
                            const float d  = fsqrt(dx * dx + dy * dy + dz * dz);
                            dsum += d; msum += fminf(d, 1.f);
                        }
                        sd[ro + r] += dsum; sm[ro + r] += msum;
                    }
                    j0 += 1024;
                    if (!more) break;
                }
            }
            // tail chunks: all-or-nothing per lane (jj multiple of 4)
            for (; j0 < N; j0 += 1024) {
                const int jj = j0 + 4 * tid;
                if (jj < N) {
                    const float4 vx = *(const float4*)(x + jj);
                    const float4 vy = *(const float4*)(y + jj);
                    const float4 vz = *(const float4*)(z + jj);
                    const float ax[4] = {vx.x, vx.y, vx.z, vx.w};
                    const float ay[4] = {vy.x, vy.y, vy.z, vy.w};
                    const float az[4] = {vz.x, vz.y, vz.z, vz.w};
#pragma unroll
                    for (int r = 0; r < 4; ++r) {
                        float dsum = 0.f, msum = 0.f;
#pragma unroll
                        for (int q = 0; q < 4; ++q) {
                            const float dx = ax[q] - xr[ro + r];
                            const float dy = ay[q] - yr[ro + r];
                            const float dz = az[q] - zr[ro + r];
                            const float d  = fsqrt(dx * dx + dy * dy + dz * dz);
                            dsum += d; msum += fminf(d, 1.f);
                        }
                        sd[ro + r] += dsum; sm[ro + r] += msum;
                    }
                }
            }
        }

        // reduce 8 rows across the block
        __shared__ float lsd[4][8];
        __shared__ float lsm[4][8];
#pragma unroll
        for (int r = 0; r < 8; ++r) {
            float a = sd[r], c = sm[r];
#pragma unroll
            for (int off = 32; off; off >>= 1) {
                a += __shfl_down(a, off);
                c += __shfl_down(c, off);
            }
            if (lane == 0) { lsd[wave][r] = a; lsm[wave][r] = c; }
        }
        __syncthreads();
        if (tid < 8) {
            const float a = lsd[0][tid] + lsd[1][tid] + lsd[2][tid] + lsd[3][tid];
            const float c = lsm[0][tid] + lsm[1][tid] + lsm[2][tid] + lsm[3][tid];
            const int   i = (tid < 4) ? (topBase + tid) : (botBase + tid - 4);
            row_sd[i] = a;
            row_sm[i] = c;
        }
    } else {
        // masked-prefix-run correction: 16 rows/block, 4 rows/wave,
        // 256 js per ballot iteration (4 per lane, float4, preloaded).
        const int cb = blockIdx.x - 1024;  // 0..511
#pragma unroll
        for (int rr = 0; rr < 4; ++rr) {
            const int   i  = 16 * cb + 4 * wave + rr;
            const float xi = x[i], yi = y[i], zi = z[i];
            float corr = 0.f;
            int   jb   = i & ~3;  // 16B-aligned chunk start
            {
                const int idx = jb + 4 * lane;
                const int ci  = (idx <= N - 4) ? idx : (N - 4);
                float4 vx = *(const float4*)(x + ci);
                float4 vy = *(const float4*)(y + ci);
                float4 vz = *(const float4*)(z + ci);
                while (true) {
                    const float ax[4] = {vx.x, vx.y, vx.z, vx.w};
                    const float ay[4] = {vy.x, vy.y, vy.z, vy.w};
                    const float az[4] = {vz.x, vz.y, vz.z, vz.w};
                    const int   myj   = jb + 4 * lane;
                    // speculative preload of next chunk (clamped, always safe)
                    {
                        const int nidx = myj + 256;
                        const int cn   = (nidx <= N - 4) ? nidx : (N - 4);
                        vx = *(const float4*)(x + cn);
                        vy = *(const float4*)(y + cn);
                        vz = *(const float4*)(z + cn);
                    }
                    float    dq[4];
                    unsigned fm = 0u;
#pragma unroll
                    for (int q = 0; q < 4; ++q) {
                        const float dx = ax[q] - xi, dy = ay[q] - yi, dz = az[q] - zi;
                        dq[q] = fsqrt(dx * dx + dy * dy + dz * dz);
                        const int j = myj + q;
                        if (j >= N || (j >= i && dq[q] > 1.f)) fm |= (1u << q);
                    }
                    const unsigned long long far = __ballot(fm != 0u);
                    const int L    = far ? __builtin_ctzll(far) : 64;
                    const int qlim = (lane < L) ? 4 : ((lane == L) ? __builtin_ctz(fm | 16u) : 0);
#pragma unroll
                    for (int q = 0; q < 4; ++q) {
                        const int j = myj + q;
                        if (q < qlim && j >= i) corr += 1.f - dq[q];
                    }
                    if (far) break;
                    jb += 256;
                }
            }
#pragma unroll
            for (int off = 32; off; off >>= 1) corr += __shfl_down(corr, off);
            if (lane == 0) row_corr[i] = corr;
        }
    }
}

// Single block, deterministic:
//   A = sum row_sd, M = sum row_sm, C = sum row_corr
//   sum_dist = 2A;  sum_relu = 2*(TRI - M) - N;  intersect = sum_relu - C
__global__ __launch_bounds__(256)
void finalize_kernel(const float* __restrict__ y, const float* __restrict__ z,
                     const float* __restrict__ row_sd, const float* __restrict__ row_sm,
                     const float* __restrict__ row_corr, float* __restrict__ out) {
    const int tid = threadIdx.x;
    float A = 0.f, M = 0.f, C = 0.f, sfix = 0.f, snoise = 0.f;
    for (int i = tid; i < N; i += 256) {
        A += row_sd[i];
        M += row_sm[i];
        C += row_corr[i];
        const float yv = y[i], zv = z[i];
        sfix += fmaxf(yv - 1.f, 0.f) + fmaxf(-1.f - yv, 0.f)
              + fmaxf(zv - 1.f, 0.f) + fmaxf(-1.f - zv, 0.f);
        if (i < N - 2) {
            const float d2y = y[i + 2] - 2.f * y[i + 1] + y[i];
            const float d2z = z[i + 2] - 2.f * z[i + 1] + z[i];
            snoise += d2y * d2y + d2z * d2z;
        }
    }
    __shared__ float s[5][256];
    s[0][tid] = A; s[1][tid] = M; s[2][tid] = C; s[3][tid] = sfix; s[4][tid] = snoise;
    __syncthreads();
    for (int st = 128; st; st >>= 1) {
        if (tid < st) {
#pragma unroll
            for (int k = 0; k < 5; ++k) s[k][tid] += s[k][tid + st];
        }
        __syncthreads();
    }
    if (tid == 0)
        out[0] = s[3][0] + (2.f * s[0][0]) / 10000.f
               + (2.f * (TRI - s[1][0]) - (float)N - s[2][0]) + 10.f * s[4][0];
}

extern "C" void kernel_launch(void* const* d_in, const int* in_sizes, int n_in,
                              void* d_out, int out_size, void* d_ws, size_t ws_size,
                              hipStream_t stream) {
    const float* x = (const float*)d_in[0];
    const float* y = (const float*)d_in[1];
    const float* z = (const float*)d_in[2];
    float* out      = (float*)d_out;
    float* row_sd   = (float*)d_ws;
    float* row_sm   = row_sd + N;
    float* row_corr = row_sm + N;

    main_kernel<<<1536, 256, 0, stream>>>(x, y, z, row_sd, row_sm, row_corr);
    finalize_kernel<<<1, 256, 0, stream>>>(y, z, row_sd, row_sm, row_corr, out);
}

// Round 7
// 29.255 us; speedup vs baseline: 1.2683x; 1.2683x over previous
//
#include <hip/hip_runtime.h>

constexpr int N = 8192;
// MIN_DIST = RADIUS*2*scale = 1.0f;  TRI = N(N+1)/2, exact in f32
constexpr float TRI = 33558528.0f;

__device__ __forceinline__ float fsqrt(float v) { return __builtin_amdgcn_sqrtf(v); }

// ws layout: p4[N] (float4) | row_sd[N] | row_sm[N] | row_corr[N] | partials[32*5]

__global__ __launch_bounds__(256)
void pack_kernel(const float* __restrict__ x, const float* __restrict__ y,
                 const float* __restrict__ z, float4* __restrict__ p4) {
    const int i = blockIdx.x * 256 + threadIdx.x;
    p4[i] = make_float4(x[i], y[i], z[i], 0.f);
}

// 2048 blocks:
//  [0,1024):    pair tiles — rows {4b..4b+3} + {N-4b-4..N-4b-1}, j >= i sweep on
//               the packed stream (1 dwordx4 per j per thread, preloaded).
//  [1024,2048): masked-prefix-run correction, 8 rows/block, 2 rows/wave,
//               128-j ballot windows with speculative preload.
__global__ __launch_bounds__(256, 8)
void main_kernel(const float4* __restrict__ p4,
                 float* __restrict__ row_sd, float* __restrict__ row_sm,
                 float* __restrict__ row_corr) {
    const int tid  = threadIdx.x;
    const int lane = tid & 63;
    const int wave = tid >> 6;

    if (blockIdx.x < 1024) {
        const int b       = blockIdx.x;
        const int topBase = 4 * b;            // 0..4092
        const int botBase = N - 4 * (b + 1);  // 8188..4096

        float xr[8], yr[8], zr[8];
#pragma unroll
        for (int r = 0; r < 4; ++r) {
            const float4 pt = p4[topBase + r];
            const float4 pb = p4[botBase + r];
            xr[r]     = pt.x; yr[r]     = pt.y; zr[r]     = pt.z;
            xr[4 + r] = pb.x; yr[4 + r] = pb.y; zr[4 + r] = pb.z;
        }
        float sd[8], sm[8];
#pragma unroll
        for (int r = 0; r < 8; ++r) { sd[r] = 0.f; sm[r] = 0.f; }

#pragma unroll
        for (int g = 0; g < 2; ++g) {
            const int base = g ? botBase : topBase;  // multiple of 4
            const int ro   = g * 4;

            // head chunk [base, base+256): predicated vs diagonal and N
            {
                const int    j  = base + tid;
                const int    jc = (j < N) ? j : (N - 1);
                const float4 p  = p4[jc];
#pragma unroll
                for (int r = 0; r < 4; ++r) {
                    const float dx = p.x - xr[ro + r], dy = p.y - yr[ro + r], dz = p.z - zr[ro + r];
                    const float d  = fsqrt(dx * dx + dy * dy + dz * dz);
                    if (j < N && tid >= r) { sd[ro + r] += d; sm[ro + r] += fminf(d, 1.f); }
                }
            }
            // full middle 256-chunks: predicate-free, preloaded
            int j0 = base + 256;
            if (j0 + 256 <= N) {
                float4 p = p4[j0 + tid];
                while (true) {
                    const float4 c    = p;
                    const bool   more = (j0 + 512 <= N);
                    if (more) p = p4[j0 + 256 + tid];
#pragma unroll
                    for (int r = 0; r < 4; ++r) {
                        const float dx = c.x - xr[ro + r], dy = c.y - yr[ro + r], dz = c.z - zr[ro + r];
                        const float d  = fsqrt(dx * dx + dy * dy + dz * dz);
                        sd[ro + r] += d; sm[ro + r] += fminf(d, 1.f);
                    }
                    j0 += 256;
                    if (!more) break;
                }
            }
            // tail partial chunk
            if (j0 < N) {
                const int j = j0 + tid;
                if (j < N) {
                    const float4 p = p4[j];
#pragma unroll
                    for (int r = 0; r < 4; ++r) {
                        const float dx = p.x - xr[ro + r], dy = p.y - yr[ro + r], dz = p.z - zr[ro + r];
                        const float d  = fsqrt(dx * dx + dy * dy + dz * dz);
                        sd[ro + r] += d; sm[ro + r] += fminf(d, 1.f);
                    }
                }
            }
        }

        // reduce 8 rows across the block
        __shared__ float lsd[4][8];
        __shared__ float lsm[4][8];
#pragma unroll
        for (int r = 0; r < 8; ++r) {
            float a = sd[r], c = sm[r];
#pragma unroll
            for (int off = 32; off; off >>= 1) {
                a += __shfl_down(a, off);
                c += __shfl_down(c, off);
            }
            if (lane == 0) { lsd[wave][r] = a; lsm[wave][r] = c; }
        }
        __syncthreads();
        if (tid < 8) {
            const float a = lsd[0][tid] + lsd[1][tid] + lsd[2][tid] + lsd[3][tid];
            const float c = lsm[0][tid] + lsm[1][tid] + lsm[2][tid] + lsm[3][tid];
            const int   i = (tid < 4) ? (topBase + tid) : (botBase + tid - 4);
            row_sd[i] = a;
            row_sm[i] = c;
        }
    } else {
        // corr: 8 rows/block, 2 rows/wave, 128-j windows, speculative preload
        const int cb = blockIdx.x - 1024;
#pragma unroll
        for (int rr = 0; rr < 2; ++rr) {
            const int    i  = 8 * cb + 2 * wave + rr;
            const float4 pi = p4[i];
            float corr = 0.f;
            int   jb   = i;
            float4 a  = p4[min(jb + lane,      N - 1)];
            float4 bq = p4[min(jb + 64 + lane, N - 1)];
            while (true) {
                const float4 na = p4[min(jb + 128 + lane, N - 1)];
                const float4 nb = p4[min(jb + 192 + lane, N - 1)];
                const int j0i = jb + lane, j1i = jb + 64 + lane;
                float dx = a.x - pi.x, dy = a.y - pi.y, dz = a.z - pi.z;
                const float d0 = fsqrt(dx * dx + dy * dy + dz * dz);
                dx = bq.x - pi.x; dy = bq.y - pi.y; dz = bq.z - pi.z;
                const float d1 = fsqrt(dx * dx + dy * dy + dz * dz);
                const unsigned long long m0 = __ballot(j0i >= N || d0 > 1.f);
                const unsigned long long m1 = __ballot(j1i >= N || d1 > 1.f);
                int stop;
                if (m0)      stop = __builtin_ctzll(m0);
                else if (m1) stop = 64 + __builtin_ctzll(m1);
                else         stop = 128;
                if (lane < stop)      corr += 1.f - d0;
                if (64 + lane < stop) corr += 1.f - d1;
                if (stop < 128) break;
                jb += 128;
                a = na; bq = nb;
            }
#pragma unroll
            for (int off = 32; off; off >>= 1) corr += __shfl_down(corr, off);
            if (lane == 0) row_corr[i] = corr;
        }
    }
}

// 32 blocks: per-block partial sums of {A, M, C, fix, noise} -> partials[b*5+c]
__global__ __launch_bounds__(256)
void partial_kernel(const float* __restrict__ y, const float* __restrict__ z,
                    const float* __restrict__ row_sd, const float* __restrict__ row_sm,
                    const float* __restrict__ row_corr, float* __restrict__ partials) {
    const int tid = threadIdx.x;
    const int i   = blockIdx.x * 256 + tid;
    float v[5];
    v[0] = row_sd[i];
    v[1] = row_sm[i];
    v[2] = row_corr[i];
    const float yv = y[i], zv = z[i];
    v[3] = fmaxf(yv - 1.f, 0.f) + fmaxf(-1.f - yv, 0.f)
         + fmaxf(zv - 1.f, 0.f) + fmaxf(-1.f - zv, 0.f);
    v[4] = 0.f;
    if (i < N - 2) {
        const float d2y = y[i + 2] - 2.f * y[i + 1] + y[i];
        const float d2z = z[i + 2] - 2.f * z[i + 1] + z[i];
        v[4] = d2y * d2y + d2z * d2z;
    }
    const int lane = tid & 63, wave = tid >> 6;
    __shared__ float s[4][5];
#pragma unroll
    for (int c = 0; c < 5; ++c) {
        float a = v[c];
#pragma unroll
        for (int off = 32; off; off >>= 1) a += __shfl_down(a, off);
        if (lane == 0) s[wave][c] = a;
    }
    __syncthreads();
    if (tid == 0) {
#pragma unroll
        for (int c = 0; c < 5; ++c)
            partials[blockIdx.x * 5 + c] = s[0][c] + s[1][c] + s[2][c] + s[3][c];
    }
}

// 1 block: final 32-way reduce + loss assembly
__global__ __launch_bounds__(64)
void final_kernel(const float* __restrict__ partials, float* __restrict__ out) {
    const int tid = threadIdx.x;
    float a[5] = {0.f, 0.f, 0.f, 0.f, 0.f};
    if (tid < 32) {
#pragma unroll
        for (int c = 0; c < 5; ++c) a[c] = partials[tid * 5 + c];
    }
#pragma unroll
    for (int c = 0; c < 5; ++c) {
#pragma unroll
        for (int off = 16; off; off >>= 1) a[c] += __shfl_down(a[c], off, 32);
    }
    if (tid == 0) {
        const float A = a[0], M = a[1], C = a[2], fix = a[3], noise = a[4];
        out[0] = fix + (2.f * A) / 10000.f
               + (2.f * (TRI - M) - (float)N - C) + 10.f * noise;
    }
}

extern "C" void kernel_launch(void* const* d_in, const int* in_sizes, int n_in,
                              void* d_out, int out_size, void* d_ws, size_t ws_size,
                              hipStream_t stream) {
    const float* x = (const float*)d_in[0];
    const float* y = (const float*)d_in[1];
    const float* z = (const float*)d_in[2];
    float* out      = (float*)d_out;
    float4* p4      = (float4*)d_ws;
    float* row_sd   = (float*)(p4 + N);
    float* row_sm   = row_sd + N;
    float* row_corr = row_sm + N;
    float* partials = row_corr + N;

    pack_kernel<<<N / 256, 256, 0, stream>>>(x, y, z, p4);
    main_kernel<<<2048, 256, 0, stream>>>(p4, row_sd, row_sm, row_corr);
    partial_kernel<<<32, 256, 0, stream>>>(y, z, row_sd, row_sm, row_corr, partials);
    final_kernel<<<1, 64, 0, stream>>>(partials, out);
}